// Round 12
// baseline (244.983 us; speedup 1.0000x reference)
//
#include <hip/hip_runtime.h>
#include <stdint.h>

// MetricLoss: B=1024, M=32, F=256, K_GRP=4
// out[0] = (1/1536) * sum_{same-group pairs i<j, m} ||x_i,m - x_j,m||^2
// out[1] = (1/522240) * sum_{g_i<g_j, m} relu(1 - ||x_i,m - x_j,m||^2)
//
// R12 = ABLATION ROUND. k_heter split into template variants, each repped
// enough to exceed the ~40us harness fills so its counters surface in top-5:
//   VARIANT 0 (x3): full pipeline (rep 0 -> real output)
//   VARIANT 1 (x8): staging + vmcnt + barriers only
//   VARIANT 2 (x8): barriers + ds_read + MFMA + epilogue only (garbage data,
//                   writes to scratch, never read)
// Outputs remain exact: k_final consumes FULL rep-0 partials only.
//
// ws layout:
//   [0,        16 MiB)   : xb  bf16 [32][1024][256]
//   [16 MiB,  +128 KiB)  : sq  f32  [32][1024]
//   [+32 KiB]            : homo_part  f32 [8192]
//   [+4.5 KiB]           : heter_part f32 [1152]   (real)
//   [+4.5 KiB]           : heter_scr  f32 [1152]   (diagnostic sink)

typedef __attribute__((ext_vector_type(4))) float f32x4;
typedef __attribute__((ext_vector_type(8))) short bf16x8;

#define XB_OFF    0u
#define SQ_OFF    16777216u
#define HOMO_OFF  16908288u   // 8192 floats
#define HETER_OFF 16941056u   // 1152 floats
#define SCR_OFF   16945664u   // 1152 floats

#define AS1 __attribute__((address_space(1)))
#define AS3 __attribute__((address_space(3)))

__device__ __forceinline__ void async16(const void* g, void* l) {
  __builtin_amdgcn_global_load_lds((const AS1 unsigned int*)(uintptr_t)g,
                                   (AS3 unsigned int*)(uintptr_t)l, 16, 0, 0);
}

__device__ __forceinline__ unsigned short f2bf(float f) {
  union { float f; unsigned u; } v; v.f = f;
  return (unsigned short)((v.u + 0x7fffu + ((v.u >> 16) & 1u)) >> 16);
}

// ---- Kernel 1 (fused convert + homo) — unchanged
__global__ __launch_bounds__(256) void k_fused(const float* __restrict__ x,
                                               unsigned short* __restrict__ xb,
                                               float* __restrict__ sq,
                                               float* __restrict__ homo_part) {
  const int task = blockIdx.x * 4 + (threadIdx.x >> 6);  // task = g*32 + m
  const int lane = threadIdx.x & 63;
  const int g = task >> 5;
  const int m = task & 31;

  const float* base = x + ((size_t)(g * 4) * 32 + m) * 256 + lane * 4;
  float4 v[4];
  float sqv[4];
  #pragma unroll
  for (int a = 0; a < 4; ++a) {
    v[a] = *(const float4*)(base + a * 8192);
    float s = v[a].x * v[a].x + v[a].y * v[a].y + v[a].z * v[a].z + v[a].w * v[a].w;
    #pragma unroll
    for (int off = 32; off; off >>= 1) s += __shfl_xor(s, off, 64);
    sqv[a] = s;
    const int i = g * 4 + a;
    if (lane == 0) sq[m * 1024 + i] = s;
    ushort4 o;
    o.x = f2bf(v[a].x); o.y = f2bf(v[a].y); o.z = f2bf(v[a].z); o.w = f2bf(v[a].w);
    *(ushort4*)(xb + ((size_t)(m * 1024 + i)) * 256 + lane * 4) = o;
  }
  const float sx = v[0].x + v[1].x + v[2].x + v[3].x;
  const float sy = v[0].y + v[1].y + v[2].y + v[3].y;
  const float sz = v[0].z + v[1].z + v[2].z + v[3].z;
  const float sw = v[0].w + v[1].w + v[2].w + v[3].w;
  float s = sx * sx + sy * sy + sz * sz + sw * sw;
  #pragma unroll
  for (int off = 32; off; off >>= 1) s += __shfl_xor(s, off, 64);
  if (lane == 0)
    homo_part[task] = 4.f * (sqv[0] + sqv[1] + sqv[2] + sqv[3]) - s;
}

// Stage one 8 KB panel-step (128 rows x 32 k) into an LDS buffer, LINEAR.
__device__ __forceinline__ void stage_panel(const unsigned short* __restrict__ X,
                                            int k0, unsigned short* buf, int tid) {
  #pragma unroll
  for (int i = 0; i < 2; ++i) {
    const int ch = i * 256 + tid;
    const int row = ch >> 2;
    const int c   = ch & 3;
    async16(X + (size_t)row * 256 + k0 + c * 8, (char*)buf + ch * 16);
  }
}

// ---- k_heter ablation template. VARIANT: 0=full, 1=stage-only, 2=compute-only
template <int VARIANT, int REPS>
__global__ __launch_bounds__(256, 4) void k_heter_v(const unsigned short* __restrict__ xb,
                                                    const float* __restrict__ sq,
                                                    float* __restrict__ heter_part,
                                                    float* __restrict__ heter_scr) {
  const int d = blockIdx.x;                  // 1152 = 8 * 144
  const int w = (d & 7) * 144 + (d >> 3);    // XCD chunk map (bijective)
  const int m = w / 36;
  int t0 = w - m * 36, r = 0;                // triangle decode: (r,c), c>=r
  while (t0 >= 8 - r) { t0 -= 8 - r; ++r; }
  const int cb = r + t0;
  const bool diag = (cb == r);

  __shared__ __align__(16) unsigned short A0[4096], A1[4096];  // 8 KB each
  __shared__ __align__(16) unsigned short B0[4096], B1[4096];
  __shared__ __align__(16) float sql[1024];                    // 4 KB sq row
  __shared__ float part[4];

  const int tid = threadIdx.x;
  const int lane = tid & 63;
  const int wid = tid >> 6;
  const int wr = wid >> 1, wc = wid & 1;     // 2x2 waves, each 64x64 output
  const int fr = lane & 15;
  const int kg = lane >> 4;

  const unsigned short* Xa = xb + ((size_t)m * 1024 + r  * 128) * 256;
  const unsigned short* Xb = xb + ((size_t)m * 1024 + cb * 128) * 256;

  for (int rep = 0; rep < REPS; ++rep) {
    __syncthreads();                         // quiesce LDS across reps

    f32x4 acc[4][4] = {};

    if (VARIANT != 2) {
      // prologue: sq row + steps 0,1
      async16(sq + m * 1024 + tid * 4, (char*)sql + tid * 16);
      stage_panel(Xa, 0, A0, tid);
      if (!diag) stage_panel(Xb, 0, B0, tid);
      stage_panel(Xa, 32, A1, tid);
      if (!diag) stage_panel(Xb, 32, B1, tid);
    } else if (rep == 0) {
      async16(sq + m * 1024 + tid * 4, (char*)sql + tid * 16);
      asm volatile("s_waitcnt vmcnt(0)" ::: "memory");
    }

    #pragma unroll
    for (int s = 0; s < 8; ++s) {
      if (VARIANT != 2) {
        if (s < 7) {
          if (diag) asm volatile("s_waitcnt vmcnt(2)" ::: "memory");
          else      asm volatile("s_waitcnt vmcnt(4)" ::: "memory");
        } else {
          asm volatile("s_waitcnt vmcnt(0)" ::: "memory");
        }
      }
      __builtin_amdgcn_s_barrier();
      asm volatile("" ::: "memory");

      if (VARIANT != 1) {
        const unsigned short* lA = (s & 1) ? A1 : A0;
        const unsigned short* lB = diag ? lA : ((s & 1) ? B1 : B0);
        bf16x8 af[4], bv[4];
        #pragma unroll
        for (int q = 0; q < 4; ++q) {
          const int ra = wr * 64 + q * 16 + fr;
          af[q] = *(const bf16x8*)(lA + ra * 32 + kg * 8);
          const int rb = wc * 64 + q * 16 + fr;
          bv[q] = *(const bf16x8*)(lB + rb * 32 + kg * 8);
        }
        #pragma unroll
        for (int ai = 0; ai < 4; ++ai)
          #pragma unroll
          for (int bj = 0; bj < 4; ++bj)
            acc[ai][bj] = __builtin_amdgcn_mfma_f32_16x16x32_bf16(af[ai], bv[bj],
                                                                  acc[ai][bj], 0, 0, 0);
      }

      asm volatile("" ::: "memory");
      __builtin_amdgcn_s_barrier();
      asm volatile("" ::: "memory");
      if (VARIANT != 2 && s + 2 < 8) {
        stage_panel(Xa, (s + 2) * 32, (s & 1) ? A1 : A0, tid);
        if (!diag) stage_panel(Xb, (s + 2) * 32, (s & 1) ? B1 : B0, tid);
      }
    }

    // epilogue
    float local = 0.f;
    if (VARIANT != 1) {
      const int ibase = r  * 128 + wr * 64;
      const int jbase = cb * 128 + wc * 64;
      float sqi[4][4];
      #pragma unroll
      for (int ai = 0; ai < 4; ++ai)
        #pragma unroll
        for (int rg = 0; rg < 4; ++rg)
          sqi[ai][rg] = sql[ibase + ai * 16 + kg * 4 + rg];
      #pragma unroll
      for (int bj = 0; bj < 4; ++bj) {
        const int j = jbase + bj * 16 + fr;
        const float sqj = sql[j];
        const int gj = j >> 2;
        #pragma unroll
        for (int ai = 0; ai < 4; ++ai)
          #pragma unroll
          for (int rg = 0; rg < 4; ++rg) {
            const int i = ibase + ai * 16 + kg * 4 + rg;
            const float dd = sqi[ai][rg] + sqj - 2.f * acc[ai][bj][rg];
            const float v = 1.f - dd;
            if (v > 0.f && gj > (i >> 2)) local += v;
          }
      }
      #pragma unroll
      for (int off = 32; off; off >>= 1) local += __shfl_xor(local, off, 64);
    }
    if (lane == 0) part[wid] = local;
    __syncthreads();
    if (tid == 0) {
      const float v = part[0] + part[1] + part[2] + part[3];
      if (VARIANT == 0 && rep == 0) heter_part[w] = v;
      else                          heter_scr[w]  = v;   // sink, never read
    }
  }
}

// ---- Kernel 3: final reduction of partials + scaling (single block)
__global__ __launch_bounds__(256) void k_final(const float* __restrict__ homo_part,
                                               const float* __restrict__ heter_part,
                                               float* __restrict__ out) {
  __shared__ float red[8];
  const int tid = threadIdx.x;
  const int lane = tid & 63;
  const int wid = tid >> 6;

  float h = 0.f;
  for (int i = tid; i < 8192; i += 256) h += homo_part[i];
  #pragma unroll
  for (int off = 32; off; off >>= 1) h += __shfl_xor(h, off, 64);
  if (lane == 0) red[wid] = h;

  float e = 0.f;
  for (int i = tid; i < 1152; i += 256) e += heter_part[i];
  #pragma unroll
  for (int off = 32; off; off >>= 1) e += __shfl_xor(e, off, 64);
  if (lane == 0) red[4 + wid] = e;

  __syncthreads();
  if (tid == 0) out[0] = (red[0] + red[1] + red[2] + red[3]) * (1.0f / 1536.0f);
  if (tid == 1) out[1] = (red[4] + red[5] + red[6] + red[7]) * (1.0f / 522240.0f);
}

extern "C" void kernel_launch(void* const* d_in, const int* in_sizes, int n_in,
                              void* d_out, int out_size, void* d_ws, size_t ws_size,
                              hipStream_t stream) {
  const float* x = (const float*)d_in[0];
  float* out = (float*)d_out;
  char* ws = (char*)d_ws;
  unsigned short* xb = (unsigned short*)(ws + XB_OFF);
  float* sq         = (float*)(ws + SQ_OFF);
  float* homo_part  = (float*)(ws + HOMO_OFF);
  float* heter_part = (float*)(ws + HETER_OFF);
  float* heter_scr  = (float*)(ws + SCR_OFF);

  k_fused<<<2048, 256, 0, stream>>>(x, xb, sq, homo_part);
  k_heter_v<0, 3><<<1152, 256, 0, stream>>>(xb, sq, heter_part, heter_scr);
  k_final<<<1, 256, 0, stream>>>(homo_part, heter_part, out);
  // diagnostics (after out is produced; sink results, never read)
  k_heter_v<1, 8><<<1152, 256, 0, stream>>>(xb, sq, heter_part, heter_scr);
  k_heter_v<2, 8><<<1152, 256, 0, stream>>>(xb, sq, heter_part, heter_scr);
}

// Round 13
// 73.340 us; speedup vs baseline: 3.3404x; 3.3404x over previous
//
#include <hip/hip_runtime.h>
#include <stdint.h>

// MetricLoss: B=1024, M=32, F=256, K_GRP=4
// out[0] = (1/1536) * sum_{same-group pairs i<j, m} ||x_i,m - x_j,m||^2
// out[1] = (1/522240) * sum_{g_i<g_j, m} relu(1 - ||x_i,m - x_j,m||^2)
//
// R13: single fused work kernel. Each of 1152 tile-blocks converts its own
// two 128x256 panels from x (f32) on the fly (reg-stage -> cvt_pk_bf16 ->
// swizzled ds_write), computes sq exactly in-block, runs the 4-step K-loop
// (single-buffered LDS, raw s_barrier, no vmcnt drains), and the diagonal
// blocks harvest the homo loss from the same MFMA accumulators.
// No global xb/sq arrays, no k_fused pass, no device-scope sync (R9 lesson).
//
// ws layout:  [0, 4.5 KiB) homo_part f32[1152]; [8 KiB, +4.5 KiB) heter_part.

typedef __attribute__((ext_vector_type(4))) float f32x4;
typedef __attribute__((ext_vector_type(8))) short bf16x8;

#define HOMO_OFF  0u
#define HETER_OFF 8192u

__device__ __forceinline__ unsigned cvtpk(float lo, float hi) {
  unsigned r;
  asm("v_cvt_pk_bf16_f32 %0, %1, %2" : "=v"(r) : "v"(lo), "v"(hi));
  return r;
}

// ---- Kernel 1: fused convert + Gram + masked losses
__global__ __launch_bounds__(256, 2) void k_all(const float* __restrict__ x,
                                                float* __restrict__ homo_part,
                                                float* __restrict__ heter_part) {
  const int d = blockIdx.x;                  // 1152 = 8 * 144
  const int w = (d & 7) * 144 + (d >> 3);    // XCD chunk map (bijective)
  const int m = w / 36;
  int t0 = w - m * 36, r = 0;                // triangle decode: (r,c), c>=r
  while (t0 >= 8 - r) { t0 -= 8 - r; ++r; }
  const int cb = r + t0;
  const bool diag = (cb == r);

  __shared__ __align__(16) unsigned short ldsA[128 * 64];  // 16 KB bf16 tile
  __shared__ __align__(16) unsigned short ldsB[128 * 64];  // 16 KB
  __shared__ float sqlA[128], sqlB[128];
  __shared__ float partE[4], partH[4];

  const int tid  = threadIdx.x;
  const int lane = tid & 63;
  const int wid  = tid >> 6;
  const int lr   = tid >> 1;     // staging row 0..127 (fixed per thread)
  const int h    = tid & 1;      // column half (32 f32)
  const int wr = wid >> 1, wc = wid & 1;     // 2x2 waves, each 64x64 output
  const int fr = lane & 15;
  const int kg = lane >> 4;

  // x[i][m][f]: row i of part m at (i*32 + m)*256
  const float* baseA = x + ((size_t)(r  * 128 + lr) * 32 + m) * 256 + h * 32;
  const float* baseB = x + ((size_t)(cb * 128 + lr) * 32 + m) * 256 + h * 32;

  float4 a[8], b[8];
  #pragma unroll
  for (int q = 0; q < 8; ++q) a[q] = *(const float4*)(baseA + q * 4);
  if (!diag) {
    #pragma unroll
    for (int q = 0; q < 8; ++q) b[q] = *(const float4*)(baseB + q * 4);
  }

  float sqa = 0.f, sqb = 0.f;
  f32x4 acc[4][4] = {};

  #pragma unroll
  for (int s = 0; s < 4; ++s) {
    // ---- convert + swizzled LDS write (chunk c at byte c^(row&7))
    #pragma unroll
    for (int j = 0; j < 4; ++j) {
      const float4 u = a[2 * j], v = a[2 * j + 1];
      sqa += u.x * u.x + u.y * u.y + u.z * u.z + u.w * u.w
           + v.x * v.x + v.y * v.y + v.z * v.z + v.w * v.w;
      uint4 pk;
      pk.x = cvtpk(u.x, u.y); pk.y = cvtpk(u.z, u.w);
      pk.z = cvtpk(v.x, v.y); pk.w = cvtpk(v.z, v.w);
      *(uint4*)((char*)ldsA + lr * 128 + ((((h << 2) + j) ^ (lr & 7)) * 16)) = pk;
    }
    if (!diag) {
      #pragma unroll
      for (int j = 0; j < 4; ++j) {
        const float4 u = b[2 * j], v = b[2 * j + 1];
        sqb += u.x * u.x + u.y * u.y + u.z * u.z + u.w * u.w
             + v.x * v.x + v.y * v.y + v.z * v.z + v.w * v.w;
        uint4 pk;
        pk.x = cvtpk(u.x, u.y); pk.y = cvtpk(u.z, u.w);
        pk.z = cvtpk(v.x, v.y); pk.w = cvtpk(v.z, v.w);
        *(uint4*)((char*)ldsB + lr * 128 + ((((h << 2) + j) ^ (lr & 7)) * 16)) = pk;
      }
    }
    // ---- refill registers with step s+1 (in flight across barriers + MFMA)
    if (s < 3) {
      #pragma unroll
      for (int q = 0; q < 8; ++q) a[q] = *(const float4*)(baseA + (s + 1) * 64 + q * 4);
      if (!diag) {
        #pragma unroll
        for (int q = 0; q < 8; ++q) b[q] = *(const float4*)(baseB + (s + 1) * 64 + q * 4);
      }
    }
    if (s == 3) {                            // exact f32 row norms
      const float ta = sqa + __shfl_xor(sqa, 1, 64);
      const float tb = sqb + __shfl_xor(sqb, 1, 64);
      if (h == 0) { sqlA[lr] = ta; sqlB[lr] = diag ? ta : tb; }
    }
    asm volatile("s_waitcnt lgkmcnt(0)" ::: "memory");
    __builtin_amdgcn_s_barrier();            // LDS tile (+ sql at s=3) visible
    asm volatile("" ::: "memory");

    const unsigned short* lB = diag ? ldsA : ldsB;
    #pragma unroll
    for (int kk = 0; kk < 2; ++kk) {
      bf16x8 af[4], bv[4];
      #pragma unroll
      for (int q = 0; q < 4; ++q) {
        const int ra = wr * 64 + q * 16 + fr;
        af[q] = *(const bf16x8*)((const char*)ldsA + ra * 128 +
                                 ((((kk << 2) + kg) ^ (ra & 7)) * 16));
        const int rb = wc * 64 + q * 16 + fr;
        bv[q] = *(const bf16x8*)((const char*)lB + rb * 128 +
                                 ((((kk << 2) + kg) ^ (rb & 7)) * 16));
      }
      #pragma unroll
      for (int ai = 0; ai < 4; ++ai)
        #pragma unroll
        for (int bj = 0; bj < 4; ++bj)
          acc[ai][bj] = __builtin_amdgcn_mfma_f32_16x16x32_bf16(af[ai], bv[bj],
                                                                acc[ai][bj], 0, 0, 0);
    }
    asm volatile("" ::: "memory");
    __builtin_amdgcn_s_barrier();            // reads done before next overwrite
    asm volatile("" ::: "memory");
  }

  // ---- epilogue: masked losses from acc + exact sq
  const int ibase = r  * 128 + wr * 64;
  const int jbase = cb * 128 + wc * 64;
  float sqi[4][4];
  #pragma unroll
  for (int ai = 0; ai < 4; ++ai)
    #pragma unroll
    for (int rg = 0; rg < 4; ++rg)
      sqi[ai][rg] = sqlA[wr * 64 + ai * 16 + kg * 4 + rg];

  float locE = 0.f, locH = 0.f;
  #pragma unroll
  for (int bj = 0; bj < 4; ++bj) {
    const int j = jbase + bj * 16 + fr;      // C/D: col = lane&15
    const float sqj = sqlB[wc * 64 + bj * 16 + fr];
    const int gj = j >> 2;
    #pragma unroll
    for (int ai = 0; ai < 4; ++ai)
      #pragma unroll
      for (int rg = 0; rg < 4; ++rg) {
        const int i = ibase + ai * 16 + kg * 4 + rg;  // row = (lane>>4)*4 + reg
        const int gi = i >> 2;
        const float dd = sqi[ai][rg] + sqj - 2.f * acc[ai][bj][rg];
        if (gj > gi) {
          const float v = 1.f - dd;
          if (v > 0.f) locE += v;
        } else if (gj == gi && j > i) {      // homo: diag tiles only, by mask
          locH += dd;
        }
      }
  }
  #pragma unroll
  for (int off = 32; off; off >>= 1) {
    locE += __shfl_xor(locE, off, 64);
    locH += __shfl_xor(locH, off, 64);
  }
  if (lane == 0) { partE[wid] = locE; partH[wid] = locH; }
  __syncthreads();
  if (tid == 0) {
    heter_part[w] = partE[0] + partE[1] + partE[2] + partE[3];
    homo_part[w]  = partH[0] + partH[1] + partH[2] + partH[3];
  }
}

// ---- Kernel 2: final reduction of partials + scaling (single block)
__global__ __launch_bounds__(256) void k_final(const float* __restrict__ homo_part,
                                               const float* __restrict__ heter_part,
                                               float* __restrict__ out) {
  __shared__ float red[8];
  const int tid = threadIdx.x;
  const int lane = tid & 63;
  const int wid = tid >> 6;

  float hsum = 0.f, esum = 0.f;
  for (int i = tid; i < 1152; i += 256) { hsum += homo_part[i]; esum += heter_part[i]; }
  #pragma unroll
  for (int off = 32; off; off >>= 1) {
    hsum += __shfl_xor(hsum, off, 64);
    esum += __shfl_xor(esum, off, 64);
  }
  if (lane == 0) { red[wid] = hsum; red[4 + wid] = esum; }
  __syncthreads();
  if (tid == 0) out[0] = (red[0] + red[1] + red[2] + red[3]) * (1.0f / 1536.0f);
  if (tid == 1) out[1] = (red[4] + red[5] + red[6] + red[7]) * (1.0f / 522240.0f);
}

extern "C" void kernel_launch(void* const* d_in, const int* in_sizes, int n_in,
                              void* d_out, int out_size, void* d_ws, size_t ws_size,
                              hipStream_t stream) {
  const float* x = (const float*)d_in[0];
  float* out = (float*)d_out;
  char* ws = (char*)d_ws;
  float* homo_part  = (float*)(ws + HOMO_OFF);
  float* heter_part = (float*)(ws + HETER_OFF);

  k_all<<<1152, 256, 0, stream>>>(x, homo_part, heter_part);
  k_final<<<1, 256, 0, stream>>>(homo_part, heter_part, out);
}

// Round 14
// 42.035 us; speedup vs baseline: 5.8281x; 1.7447x over previous
//
#include <hip/hip_runtime.h>
#include <stdint.h>

// MetricLoss: B=1024, M=32, F=256, K_GRP=4
// out[0] = (1/1536) * sum_{same-group pairs i<j, m} ||x_i,m - x_j,m||^2
// out[1] = (1/522240) * sum_{g_i<g_j, m} relu(1 - ||x_i,m - x_j,m||^2)
//
// R14: BARRIER-FREE k_heter. Each wave stages its own A/B 64x32 sub-tiles
// into wave-private LDS (global_load_lds is wave-scoped), double-buffered,
// paced only by its own counted vmcnt. Zero s_barrier in the K-loop ->
// no lockstep pacing (R12 ablation: FULL 31us >> stage 12 + compute 5).
// 2x staged bytes, but L2-served. Plain __launch_bounds__(256): R13 showed
// (256,2) caps VGPR at 128 -> 65 MB scratch spills.
//
// ws layout:
//   [0,        16 MiB)   : xb  bf16 [32][1024][256]
//   [16 MiB,  +128 KiB)  : sq  f32  [32][1024]
//   [+32 KiB]            : homo_part  f32 [8192]
//   [+4.5 KiB]           : heter_part f32 [1152]

typedef __attribute__((ext_vector_type(4))) float f32x4;
typedef __attribute__((ext_vector_type(8))) short bf16x8;

#define XB_OFF    0u
#define SQ_OFF    16777216u
#define HOMO_OFF  16908288u   // 8192 floats
#define HETER_OFF 16941056u   // 1152 floats

#define AS1 __attribute__((address_space(1)))
#define AS3 __attribute__((address_space(3)))

__device__ __forceinline__ void async16(const void* g, void* l) {
  __builtin_amdgcn_global_load_lds((const AS1 unsigned int*)(uintptr_t)g,
                                   (AS3 unsigned int*)(uintptr_t)l, 16, 0, 0);
}

__device__ __forceinline__ unsigned short f2bf(float f) {
  union { float f; unsigned u; } v; v.f = f;
  return (unsigned short)((v.u + 0x7fffu + ((v.u >> 16) & 1u)) >> 16);
}

// ---- Kernel 1 (fused convert + homo) — unchanged (proven, ~BW-bound)
__global__ __launch_bounds__(256) void k_fused(const float* __restrict__ x,
                                               unsigned short* __restrict__ xb,
                                               float* __restrict__ sq,
                                               float* __restrict__ homo_part) {
  const int task = blockIdx.x * 4 + (threadIdx.x >> 6);  // task = g*32 + m
  const int lane = threadIdx.x & 63;
  const int g = task >> 5;
  const int m = task & 31;

  const float* base = x + ((size_t)(g * 4) * 32 + m) * 256 + lane * 4;
  float4 v[4];
  float sqv[4];
  #pragma unroll
  for (int a = 0; a < 4; ++a) {
    v[a] = *(const float4*)(base + a * 8192);
    float s = v[a].x * v[a].x + v[a].y * v[a].y + v[a].z * v[a].z + v[a].w * v[a].w;
    #pragma unroll
    for (int off = 32; off; off >>= 1) s += __shfl_xor(s, off, 64);
    sqv[a] = s;
    const int i = g * 4 + a;
    if (lane == 0) sq[m * 1024 + i] = s;
    ushort4 o;
    o.x = f2bf(v[a].x); o.y = f2bf(v[a].y); o.z = f2bf(v[a].z); o.w = f2bf(v[a].w);
    *(ushort4*)(xb + ((size_t)(m * 1024 + i)) * 256 + lane * 4) = o;
  }
  const float sx = v[0].x + v[1].x + v[2].x + v[3].x;
  const float sy = v[0].y + v[1].y + v[2].y + v[3].y;
  const float sz = v[0].z + v[1].z + v[2].z + v[3].z;
  const float sw = v[0].w + v[1].w + v[2].w + v[3].w;
  float s = sx * sx + sy * sy + sz * sz + sw * sw;
  #pragma unroll
  for (int off = 32; off; off >>= 1) s += __shfl_xor(s, off, 64);
  if (lane == 0)
    homo_part[task] = 4.f * (sqv[0] + sqv[1] + sqv[2] + sqv[3]) - s;
}

// Stage a wave-private 64x32 bf16 sub-tile (4 KB) step. 4 loads/lane.
// Chunk swizzle: LDS chunk (row, c) holds global chunk c^((row>>1)&3)
// -> the b128 fragment read (16 lanes, fixed kg) is 2-way (free).
__device__ __forceinline__ void stage_wtile(const unsigned short* __restrict__ G,
                                            int k0, char* buf, int lane) {
  #pragma unroll
  for (int i = 0; i < 4; ++i) {
    const int ch = i * 64 + lane;            // 256 chunks of 16B
    const int row = ch >> 2;                 // 0..63
    const int gc = (ch & 3) ^ ((row >> 1) & 3);
    async16(G + (size_t)row * 256 + k0 + gc * 8, buf + ch * 16);
  }
}

// ---- Kernel 2: heter loss, wave-private barrier-free pipeline.
__global__ __launch_bounds__(256) void k_heter(const unsigned short* __restrict__ xb,
                                               const float* __restrict__ sq,
                                               float* __restrict__ heter_part) {
  const int d = blockIdx.x;                  // 1152 = 8 * 144
  const int w = (d & 7) * 144 + (d >> 3);    // XCD chunk map (bijective)
  const int m = w / 36;
  int t0 = w - m * 36, r = 0;                // triangle decode: (r,c), c>=r
  while (t0 >= 8 - r) { t0 -= 8 - r; ++r; }
  const int cb = r + t0;
  const bool diag = (cb == r);

  __shared__ __align__(16) char lds[65536];  // [wave][A0,B0,A1,B1][4096]
  __shared__ float part[4];

  const int tid = threadIdx.x;
  const int lane = tid & 63;
  const int wid = tid >> 6;
  const int wr = wid >> 1, wc = wid & 1;     // 2x2 waves, each 64x64 output
  const int fr = lane & 15;
  const int kg = lane >> 4;

  float local = 0.f;
  const bool skip = diag && wr == 1 && wc == 0;   // provably-zero quadrant

  if (!skip) {
    const bool share = diag && (wr == wc);   // A rows == B rows -> stage once
    const unsigned short* Ag = xb + ((size_t)m * 1024 + r  * 128 + wr * 64) * 256;
    const unsigned short* Bg = xb + ((size_t)m * 1024 + cb * 128 + wc * 64) * 256;
    char* const base = lds + wid * 16384;
    char* const A0 = base, * const B0 = base + 4096;
    char* const A1 = base + 8192, * const B1 = base + 12288;

    // prologue: steps 0,1 in flight (wave-private, no coordination needed)
    stage_wtile(Ag, 0, A0, lane);
    if (!share) stage_wtile(Bg, 0, B0, lane);
    stage_wtile(Ag, 32, A1, lane);
    if (!share) stage_wtile(Bg, 32, B1, lane);

    const int rch = (kg ^ ((fr >> 1) & 3)) << 4;   // swizzled chunk byte
    f32x4 acc[4][4] = {};

    #pragma unroll
    for (int s = 0; s < 8; ++s) {
      if (s < 7) {
        if (share) asm volatile("s_waitcnt vmcnt(4)" ::: "memory");
        else       asm volatile("s_waitcnt vmcnt(8)" ::: "memory");
      } else {
        asm volatile("s_waitcnt vmcnt(0)" ::: "memory");
      }
      const char* lA = (s & 1) ? A1 : A0;
      const char* lB = share ? lA : ((s & 1) ? B1 : B0);
      bf16x8 af[4], bv[4];
      #pragma unroll
      for (int q = 0; q < 4; ++q) {
        const int rloc = q * 16 + fr;        // local row 0..63
        af[q] = *(const bf16x8*)(lA + rloc * 64 + rch);
        bv[q] = *(const bf16x8*)(lB + rloc * 64 + rch);
      }
      #pragma unroll
      for (int ai = 0; ai < 4; ++ai)
        #pragma unroll
        for (int bj = 0; bj < 4; ++bj)
          acc[ai][bj] = __builtin_amdgcn_mfma_f32_16x16x32_bf16(af[ai], bv[bj],
                                                                acc[ai][bj], 0, 0, 0);
      // fragment regs hold the data; safe to overwrite the buffer afterwards
      asm volatile("s_waitcnt lgkmcnt(0)" ::: "memory");
      if (s + 2 < 8) {
        stage_wtile(Ag, (s + 2) * 32, (s & 1) ? A1 : A0, lane);
        if (!share) stage_wtile(Bg, (s + 2) * 32, (s & 1) ? B1 : B0, lane);
      }
    }

    // epilogue: relu(1 - (sq_i + sq_j - 2*dot)), strict group mask
    const int ibase = r  * 128 + wr * 64;
    const int jbase = cb * 128 + wc * 64;
    const float* sqm = sq + m * 1024;
    float sqi[4][4];
    #pragma unroll
    for (int ai = 0; ai < 4; ++ai)
      #pragma unroll
      for (int rg = 0; rg < 4; ++rg)
        sqi[ai][rg] = sqm[ibase + ai * 16 + kg * 4 + rg];
    #pragma unroll
    for (int bj = 0; bj < 4; ++bj) {
      const int j = jbase + bj * 16 + fr;    // C/D: col = lane&15
      const float sqj = sqm[j];
      const int gj = j >> 2;
      #pragma unroll
      for (int ai = 0; ai < 4; ++ai)
        #pragma unroll
        for (int rg = 0; rg < 4; ++rg) {
          const int i = ibase + ai * 16 + kg * 4 + rg;  // row=(lane>>4)*4+reg
          const float dd = sqi[ai][rg] + sqj - 2.f * acc[ai][bj][rg];
          const float v = 1.f - dd;
          if (v > 0.f && gj > (i >> 2)) local += v;
        }
    }
    #pragma unroll
    for (int off = 32; off; off >>= 1) local += __shfl_xor(local, off, 64);
  }

  if (lane == 0) part[wid] = local;
  __syncthreads();
  if (tid == 0) heter_part[w] = part[0] + part[1] + part[2] + part[3];
}

// ---- Kernel 3: final reduction of partials + scaling (single block)
__global__ __launch_bounds__(256) void k_final(const float* __restrict__ homo_part,
                                               const float* __restrict__ heter_part,
                                               float* __restrict__ out) {
  __shared__ float red[8];
  const int tid = threadIdx.x;
  const int lane = tid & 63;
  const int wid = tid >> 6;

  float h = 0.f;
  for (int i = tid; i < 8192; i += 256) h += homo_part[i];
  #pragma unroll
  for (int off = 32; off; off >>= 1) h += __shfl_xor(h, off, 64);
  if (lane == 0) red[wid] = h;

  float e = 0.f;
  for (int i = tid; i < 1152; i += 256) e += heter_part[i];
  #pragma unroll
  for (int off = 32; off; off >>= 1) e += __shfl_xor(e, off, 64);
  if (lane == 0) red[4 + wid] = e;

  __syncthreads();
  if (tid == 0) out[0] = (red[0] + red[1] + red[2] + red[3]) * (1.0f / 1536.0f);
  if (tid == 1) out[1] = (red[4] + red[5] + red[6] + red[7]) * (1.0f / 522240.0f);
}

extern "C" void kernel_launch(void* const* d_in, const int* in_sizes, int n_in,
                              void* d_out, int out_size, void* d_ws, size_t ws_size,
                              hipStream_t stream) {
  const float* x = (const float*)d_in[0];
  float* out = (float*)d_out;
  char* ws = (char*)d_ws;
  unsigned short* xb = (unsigned short*)(ws + XB_OFF);
  float* sq         = (float*)(ws + SQ_OFF);
  float* homo_part  = (float*)(ws + HOMO_OFF);
  float* heter_part = (float*)(ws + HETER_OFF);

  k_fused<<<2048, 256, 0, stream>>>(x, xb, sq, homo_part);
  k_heter<<<1152, 256, 0, stream>>>(xb, sq, heter_part);
  k_final<<<1, 256, 0, stream>>>(homo_part, heter_part, out);
}

// Round 15
// 35.080 us; speedup vs baseline: 6.9837x; 1.1983x over previous
//
#include <hip/hip_runtime.h>
#include <stdint.h>

// MetricLoss: B=1024, M=32, F=256, K_GRP=4
// out[0] = (1/1536) * sum_{same-group pairs i<j, m} ||x_i,m - x_j,m||^2
// out[1] = (1/522240) * sum_{g_i<g_j, m} relu(1 - ||x_i,m - x_j,m||^2)
//
// R15 = R13 fixed: single fused work kernel (no xb/sq arrays, no k_fused
// pass). 512-thread / 8-wave blocks keep VGPR ~115 < 128 cap of
// __launch_bounds__(512,4) -> no spills (R13's failure), 2 blocks/CU.
// Per step: convert cur regs->LDS bf16, issue next-step loads (in flight
// across MFMA via raw lgkmcnt+s_barrier, NOT __syncthreads which drains
// vmcnt), 8 MFMA per wave. sq exact in regs; homo from diag blocks' acc
// (validated in R13). No device-scope sync (R9 lesson).
//
// ws layout: [0) homo_part f32[1152]; [8 KiB) heter_part f32[1152].

typedef __attribute__((ext_vector_type(4))) float f32x4;
typedef __attribute__((ext_vector_type(8))) short bf16x8;

#define HOMO_OFF  0u
#define HETER_OFF 8192u

__device__ __forceinline__ unsigned cvtpk(float lo, float hi) {
  unsigned r;
  asm("v_cvt_pk_bf16_f32 %0, %1, %2" : "=v"(r) : "v"(lo), "v"(hi));
  return r;
}

__device__ __forceinline__ float sq8(const float4& u, const float4& v) {
  return u.x * u.x + u.y * u.y + u.z * u.z + u.w * u.w
       + v.x * v.x + v.y * v.y + v.z * v.z + v.w * v.w;
}

__device__ __forceinline__ uint4 pk8(const float4& u, const float4& v) {
  uint4 p;
  p.x = cvtpk(u.x, u.y); p.y = cvtpk(u.z, u.w);
  p.z = cvtpk(v.x, v.y); p.w = cvtpk(v.z, v.w);
  return p;
}

// ---- Kernel 1: fused convert + Gram + masked losses (8 waves, 128x128 tile)
__global__ __launch_bounds__(512, 4) void k_main(const float* __restrict__ x,
                                                 float* __restrict__ homo_part,
                                                 float* __restrict__ heter_part) {
  const int d = blockIdx.x;                  // 1152 = 8 * 144
  const int w = (d & 7) * 144 + (d >> 3);    // XCD chunk map (bijective)
  const int m = w / 36;
  int t0 = w - m * 36, r = 0;                // triangle decode: (r,c), c>=r
  while (t0 >= 8 - r) { t0 -= 8 - r; ++r; }
  const int cb = r + t0;
  const bool diag = (cb == r);

  __shared__ __align__(16) unsigned short bA[2][128 * 32];  // 8 KB x2 bf16
  __shared__ __align__(16) unsigned short bB[2][128 * 32];
  __shared__ float sqlA[128], sqlB[128];
  __shared__ float partE[8], partH[8];

  const int tid  = threadIdx.x;
  const int lane = tid & 63;
  const int wid  = tid >> 6;                 // 0..7
  const int wr = wid >> 2, wc = wid & 3;     // wave quadrant: 64 rows x 32 cols
  const int fr = lane & 15;
  const int kg = lane >> 4;

  const int srow = tid >> 2;                 // staging row 0..127
  const int sch  = tid & 3;                  // 8-f32 chunk 0..3

  // x[i][m][f] at i*8192 + m*256 + f
  const float* pa = x + (size_t)(r  * 128 + srow) * 8192 + m * 256 + sch * 8;
  const float* pb = x + (size_t)(cb * 128 + srow) * 8192 + m * 256 + sch * 8;

  float4 a0 = *(const float4*)(pa), a1 = *(const float4*)(pa + 4);
  float4 c0, c1;
  if (!diag) { c0 = *(const float4*)(pb); c1 = *(const float4*)(pb + 4); }

  float rsqA = 0.f, rsqB = 0.f;
  f32x4 acc[4][2] = {};

  const int wb = srow * 64 + sch * 16;       // LDS write byte (linear [128][32])

  #pragma unroll
  for (int s = 0; s < 8; ++s) {
    unsigned short* const LA = bA[s & 1];
    unsigned short* const LB = bB[s & 1];
    // convert current regs -> LDS bf16; exact sq accumulates in regs
    rsqA += sq8(a0, a1);
    *(uint4*)((char*)LA + wb) = pk8(a0, a1);
    if (!diag) {
      rsqB += sq8(c0, c1);
      *(uint4*)((char*)LB + wb) = pk8(c0, c1);
    }
    // issue next-step loads; they stay in flight across the MFMA phase
    if (s < 7) {
      a0 = *(const float4*)(pa + (s + 1) * 32);
      a1 = *(const float4*)(pa + (s + 1) * 32 + 4);
      if (!diag) {
        c0 = *(const float4*)(pb + (s + 1) * 32);
        c1 = *(const float4*)(pb + (s + 1) * 32 + 4);
      }
    }
    // raw barrier: wait only LDS writes (NOT the pending global loads)
    asm volatile("s_waitcnt lgkmcnt(0)" ::: "memory");
    __builtin_amdgcn_s_barrier();
    asm volatile("" ::: "memory");

    const unsigned short* lB = diag ? LA : LB;
    bf16x8 af[4], bv[2];
    #pragma unroll
    for (int q = 0; q < 4; ++q)
      af[q] = *(const bf16x8*)((const char*)LA + (wr * 64 + q * 16 + fr) * 64 + kg * 16);
    #pragma unroll
    for (int bq = 0; bq < 2; ++bq)
      bv[bq] = *(const bf16x8*)((const char*)lB + (wc * 32 + bq * 16 + fr) * 64 + kg * 16);
    #pragma unroll
    for (int q = 0; q < 4; ++q)
      #pragma unroll
      for (int bq = 0; bq < 2; ++bq)
        acc[q][bq] = __builtin_amdgcn_mfma_f32_16x16x32_bf16(af[q], bv[bq],
                                                             acc[q][bq], 0, 0, 0);
    asm volatile("" ::: "memory");
    __builtin_amdgcn_s_barrier();            // reads done before next overwrite
    asm volatile("" ::: "memory");
  }

  // exact row norms -> LDS (reduce across the 4 threads sharing a row)
  rsqA += __shfl_xor(rsqA, 1, 64); rsqA += __shfl_xor(rsqA, 2, 64);
  rsqB += __shfl_xor(rsqB, 1, 64); rsqB += __shfl_xor(rsqB, 2, 64);
  if (sch == 0) { sqlA[srow] = rsqA; sqlB[srow] = diag ? rsqA : rsqB; }
  __syncthreads();

  // epilogue: masked losses from acc + exact sq
  const int ibase = r  * 128 + wr * 64;
  const int jbase = cb * 128 + wc * 32;
  float sqi[4][4];
  #pragma unroll
  for (int q = 0; q < 4; ++q)
    #pragma unroll
    for (int rg = 0; rg < 4; ++rg)
      sqi[q][rg] = sqlA[wr * 64 + q * 16 + kg * 4 + rg];

  float locE = 0.f, locH = 0.f;
  #pragma unroll
  for (int bq = 0; bq < 2; ++bq) {
    const int j = jbase + bq * 16 + fr;      // C/D: col = lane&15
    const float sqj = sqlB[wc * 32 + bq * 16 + fr];
    const int gj = j >> 2;
    #pragma unroll
    for (int q = 0; q < 4; ++q)
      #pragma unroll
      for (int rg = 0; rg < 4; ++rg) {
        const int i = ibase + q * 16 + kg * 4 + rg;   // row = (lane>>4)*4 + reg
        const int gi = i >> 2;
        const float dd = sqi[q][rg] + sqj - 2.f * acc[q][bq][rg];
        if (gj > gi) {
          const float v = 1.f - dd;
          if (v > 0.f) locE += v;
        } else if (gj == gi && j > i) {      // homo: fires only in diag tiles
          locH += dd;
        }
      }
  }
  #pragma unroll
  for (int off = 32; off; off >>= 1) {
    locE += __shfl_xor(locE, off, 64);
    locH += __shfl_xor(locH, off, 64);
  }
  if (lane == 0) { partE[wid] = locE; partH[wid] = locH; }
  __syncthreads();
  if (tid == 0) {
    float e = 0.f, h = 0.f;
    #pragma unroll
    for (int q = 0; q < 8; ++q) { e += partE[q]; h += partH[q]; }
    heter_part[w] = e;
    homo_part[w]  = h;
  }
}

// ---- Kernel 2: final reduction of partials + scaling (single block)
__global__ __launch_bounds__(256) void k_final(const float* __restrict__ homo_part,
                                               const float* __restrict__ heter_part,
                                               float* __restrict__ out) {
  __shared__ float red[8];
  const int tid = threadIdx.x;
  const int lane = tid & 63;
  const int wid = tid >> 6;

  float hsum = 0.f, esum = 0.f;
  for (int i = tid; i < 1152; i += 256) { hsum += homo_part[i]; esum += heter_part[i]; }
  #pragma unroll
  for (int off = 32; off; off >>= 1) {
    hsum += __shfl_xor(hsum, off, 64);
    esum += __shfl_xor(esum, off, 64);
  }
  if (lane == 0) { red[wid] = hsum; red[4 + wid] = esum; }
  __syncthreads();
  if (tid == 0) out[0] = (red[0] + red[1] + red[2] + red[3]) * (1.0f / 1536.0f);
  if (tid == 1) out[1] = (red[4] + red[5] + red[6] + red[7]) * (1.0f / 522240.0f);
}

extern "C" void kernel_launch(void* const* d_in, const int* in_sizes, int n_in,
                              void* d_out, int out_size, void* d_ws, size_t ws_size,
                              hipStream_t stream) {
  const float* x = (const float*)d_in[0];
  float* out = (float*)d_out;
  char* ws = (char*)d_ws;
  float* homo_part  = (float*)(ws + HOMO_OFF);
  float* heter_part = (float*)(ws + HETER_OFF);

  k_main<<<1152, 512, 0, stream>>>(x, homo_part, heter_part);
  k_final<<<1, 256, 0, stream>>>(homo_part, heter_part, out);
}